// Round 1
// baseline (436.039 us; speedup 1.0000x reference)
//
#include <hip/hip_runtime.h>
#include <math.h>

#define EMB 1024
#define HID 1024
#define VOCAB 50257
#define HOUT_OFF VOCAB
#define COUT_OFF (VOCAB + 2*HID)
#define ROWS_PER_BLOCK 16
#define NB_LOGITS ((VOCAB + ROWS_PER_BLOCK - 1) / ROWS_PER_BLOCK)

__device__ __forceinline__ float wave_reduce(float v) {
#pragma unroll
    for (int o = 32; o > 0; o >>= 1) v += __shfl_down(v, o);
    return v;
}

__device__ __forceinline__ float sigmoidf_(float x) { return 1.0f / (1.0f + expf(-x)); }

// One block per hidden unit r. Wave w (0..3) computes gate w (i/f/g/o):
//   gate = dot(W_ih[w*HID+r], x) + dot(W_hh[w*HID+r], h_prev) + b_ih + b_hh
// Thread 0 applies the LSTM cell and writes h,c to d_out (+ h to ws).
__global__ __launch_bounds__(256) void lstm_gemv(
    const float* __restrict__ Wih, const float* __restrict__ Whh,
    const float* __restrict__ bih, const float* __restrict__ bhh,
    const float* __restrict__ emb, const int* __restrict__ word,
    const float* __restrict__ x_in,            // null for layer 0 (use emb+relu)
    const float* __restrict__ h_prev, const float* __restrict__ c_prev,
    float* __restrict__ h_ws, float* __restrict__ out, int layer)
{
    const int r    = blockIdx.x;          // hidden unit 0..HID-1
    const int wave = threadIdx.x >> 6;    // 0..3 -> gate i/f/g/o
    const int lane = threadIdx.x & 63;
    const int row  = wave * HID + r;

    // 16 floats of x and h per lane (4 x float4), covering the 1024-dot.
    float4 xv[4], hv[4];
    if (x_in != nullptr) {
#pragma unroll
        for (int j = 0; j < 4; ++j) xv[j] = ((const float4*)x_in)[j*64 + lane];
    } else {
        const float4* e = (const float4*)(emb + (size_t)word[0] * EMB);
#pragma unroll
        for (int j = 0; j < 4; ++j) {
            float4 v = e[j*64 + lane];
            v.x = fmaxf(v.x, 0.f); v.y = fmaxf(v.y, 0.f);
            v.z = fmaxf(v.z, 0.f); v.w = fmaxf(v.w, 0.f);
            xv[j] = v;
        }
    }
#pragma unroll
    for (int j = 0; j < 4; ++j) hv[j] = ((const float4*)h_prev)[j*64 + lane];

    const float4* wih = (const float4*)(Wih + (size_t)row * EMB);
    const float4* whh = (const float4*)(Whh + (size_t)row * HID);
    float acc = 0.f;
#pragma unroll
    for (int j = 0; j < 4; ++j) {
        float4 a = wih[j*64 + lane];
        acc += a.x*xv[j].x + a.y*xv[j].y + a.z*xv[j].z + a.w*xv[j].w;
        float4 b = whh[j*64 + lane];
        acc += b.x*hv[j].x + b.y*hv[j].y + b.z*hv[j].z + b.w*hv[j].w;
    }
    acc = wave_reduce(acc);

    __shared__ float gates[4];
    if (lane == 0) gates[wave] = acc + bih[row] + bhh[row];
    __syncthreads();

    if (threadIdx.x == 0) {
        float ig = sigmoidf_(gates[0]);
        float fg = sigmoidf_(gates[1]);
        float gg = tanhf(gates[2]);
        float og = sigmoidf_(gates[3]);
        float c  = fg * c_prev[r] + ig * gg;
        float h  = og * tanhf(c);
        h_ws[r] = h;
        out[HOUT_OFF + layer * HID + r] = h;
        out[COUT_OFF + layer * HID + r] = c;
    }
}

// logits[row] = dot(W_out[row], h2) + b_out[row]; 4 rows per wave, 16 per
// block. Each block also emits an online-softmax partial (max, sumexp).
__global__ __launch_bounds__(256) void logits_gemv(
    const float* __restrict__ W, const float* __restrict__ b,
    const float* __restrict__ x, float* __restrict__ out,
    float* __restrict__ partials)
{
    const int wave = threadIdx.x >> 6;
    const int lane = threadIdx.x & 63;

    float4 xv[4];
#pragma unroll
    for (int j = 0; j < 4; ++j) xv[j] = ((const float4*)x)[j*64 + lane];

    float m = -INFINITY, s = 0.f;
    const int base = blockIdx.x * ROWS_PER_BLOCK + wave * 4;
#pragma unroll
    for (int k = 0; k < 4; ++k) {
        int row = base + k;
        if (row >= VOCAB) break;   // wave-uniform
        const float4* wr = (const float4*)(W + (size_t)row * HID);
        float acc = 0.f;
#pragma unroll
        for (int j = 0; j < 4; ++j) {
            float4 a = wr[j*64 + lane];
            acc += a.x*xv[j].x + a.y*xv[j].y + a.z*xv[j].z + a.w*xv[j].w;
        }
        acc = wave_reduce(acc);
        if (lane == 0) {
            float logit = acc + b[row];
            out[row] = logit;
            float nm = fmaxf(m, logit);
            s = s * expf(m - nm) + expf(logit - nm);
            m = nm;
        }
    }

    __shared__ float ms[4], ss[4];
    if (lane == 0) { ms[wave] = m; ss[wave] = s; }
    __syncthreads();
    if (threadIdx.x == 0) {
        float M = ms[0], S = ss[0];     // wave 0 always has >=1 valid row
#pragma unroll
        for (int w = 1; w < 4; ++w) {
            float nm = fmaxf(M, ms[w]);
            S = S * expf(M - nm) + ss[w] * expf(ms[w] - nm);
            M = nm;
        }
        partials[2 * blockIdx.x]     = M;
        partials[2 * blockIdx.x + 1] = S;
    }
}

__global__ __launch_bounds__(256) void softmax_combine(
    const float* __restrict__ partials, int nb, float* __restrict__ s_out)
{
    float M = -INFINITY, S = 0.f;
    for (int p = threadIdx.x; p < nb; p += 256) {
        float m = partials[2*p], s = partials[2*p + 1];
        float nm = fmaxf(M, m);
        S = S * expf(M - nm) + s * expf(m - nm);
        M = nm;
    }
    __shared__ float ms[256], ss[256];
    ms[threadIdx.x] = M; ss[threadIdx.x] = S;
    __syncthreads();
    for (int o = 128; o > 0; o >>= 1) {
        if (threadIdx.x < (unsigned)o) {
            float m2 = ms[threadIdx.x + o], s2 = ss[threadIdx.x + o];
            float m1 = ms[threadIdx.x];
            float nm = fmaxf(m1, m2);
            ss[threadIdx.x] = ss[threadIdx.x] * expf(m1 - nm) + s2 * expf(m2 - nm);
            ms[threadIdx.x] = nm;
        }
        __syncthreads();
    }
    if (threadIdx.x == 0) s_out[0] = ms[0] + logf(ss[0]);
}

__global__ __launch_bounds__(256) void logsoftmax_sub(
    float* __restrict__ out, const float* __restrict__ s_ptr, int n)
{
    int i = blockIdx.x * 256 + threadIdx.x;
    if (i < n) out[i] -= s_ptr[0];
}

extern "C" void kernel_launch(void* const* d_in, const int* in_sizes, int n_in,
                              void* d_out, int out_size, void* d_ws, size_t ws_size,
                              hipStream_t stream)
{
    const int*   word = (const int*)  d_in[0];
    const float* h0   = (const float*)d_in[1];
    const float* c0   = (const float*)d_in[2];
    const float* emb  = (const float*)d_in[3];
    const float* Wih0 = (const float*)d_in[4];
    const float* Whh0 = (const float*)d_in[5];
    const float* bih0 = (const float*)d_in[6];
    const float* bhh0 = (const float*)d_in[7];
    const float* Wih1 = (const float*)d_in[8];
    const float* Whh1 = (const float*)d_in[9];
    const float* bih1 = (const float*)d_in[10];
    const float* bhh1 = (const float*)d_in[11];
    const float* Wout = (const float*)d_in[12];
    const float* bout = (const float*)d_in[13];

    float* out = (float*)d_out;
    float* ws  = (float*)d_ws;
    float* h1       = ws;                      // HID floats
    float* h2       = ws + HID;                // HID floats
    float* partials = ws + 2 * HID;            // 2*NB_LOGITS floats
    float* s_ptr    = ws + 2 * HID + 2 * NB_LOGITS;

    lstm_gemv<<<HID, 256, 0, stream>>>(Wih0, Whh0, bih0, bhh0, emb, word,
                                       nullptr, h0, c0, h1, out, 0);
    lstm_gemv<<<HID, 256, 0, stream>>>(Wih1, Whh1, bih1, bhh1, emb, word,
                                       h1, h0 + HID, c0 + HID, h2, out, 1);
    logits_gemv<<<NB_LOGITS, 256, 0, stream>>>(Wout, bout, h2, out, partials);
    softmax_combine<<<1, 256, 0, stream>>>(partials, NB_LOGITS, s_ptr);
    logsoftmax_sub<<<(VOCAB + 255) / 256, 256, 0, stream>>>(out, s_ptr, VOCAB);
}